// Round 6
// baseline (344.703 us; speedup 1.0000x reference)
//
#include <hip/hip_runtime.h>
#include <stdint.h>

// PointNet EdgeConv, 2 layers. Round 6.
// R1: scatter atomics bound (1.6 GB memory-side writes).      4209 us
// R2: gather-per-node spilled (VGPR 256, 9.6 GB scratch).    13742 us
// R3: sorted CSR + block-segmented max in LDS.                 646 us
// R4: scalar-pipe weights, no LDS weights, atomic-free sort.   378 us
// R5: packed v_pk_fma_f32 (g-inner order).                     337 us
// R6: i/h-OUTER loop order (broadcast once per input elem, 16 live v2f accs);
//     sm stored as packed bf16 (LDS 33.8->17 KB, pk_max_f32 phase 2);
//     occupancy bounds (L1: 8 waves/EU, L2: 5); float4-padded pos gathers.

#define BS 256

typedef float v2f __attribute__((ext_vector_type(2)));

__device__ __forceinline__ unsigned ordenc(float f) {
    unsigned u = __float_as_uint(f);
    return (u & 0x80000000u) ? ~u : (u | 0x80000000u);
}
__device__ __forceinline__ float orddec(unsigned o) {
    unsigned u = (o & 0x80000000u) ? (o ^ 0x80000000u) : ~o;
    return __uint_as_float(u);
}
#define ORD_NEG_INF 0x007FFFFFu  // ordenc(-inf)

// pack two fp32 -> two bf16 (RNE), low = x, high = y
__device__ __forceinline__ unsigned pack_bf16_rne(float x, float y) {
    unsigned ux = __float_as_uint(x), uy = __float_as_uint(y);
    ux = ux + 0x7FFFu + ((ux >> 16) & 1u);
    uy = uy + 0x7FFFu + ((uy >> 16) & 1u);
    return (ux >> 16) | (uy & 0xFFFF0000u);
}

// ---------------- utility kernels ----------------

// zero cnt, init agg buffers, build float4-padded pos
__global__ __launch_bounds__(BS) void init_kernel(const float* __restrict__ pos,
                                                  float4* __restrict__ pos4,
                                                  int* __restrict__ cnt, int N,
                                                  unsigned* __restrict__ a,
                                                  unsigned* __restrict__ b, int n32) {
    int i = blockIdx.x * BS + threadIdx.x;
    if (i < N) {
        cnt[i] = 0;
        pos4[i] = make_float4(pos[3 * i], pos[3 * i + 1], pos[3 * i + 2], 0.0f);
    }
    if (i < n32) {
        a[i] = ORD_NEG_INF;
        b[i] = ORD_NEG_INF;
    }
}

__global__ __launch_bounds__(BS) void finalize_kernel(unsigned* __restrict__ buf, int n) {
    int i = blockIdx.x * BS + threadIdx.x;
    if (i < n) {
        float v = orddec(buf[i]);
        reinterpret_cast<float*>(buf)[i] = fmaxf(v, 0.0f);
    }
}

// ---------------- counting sort (CSR build) ----------------

__global__ __launch_bounds__(BS) void hist_rank_kernel(const int* __restrict__ ei, int E,
                                                       int* __restrict__ cnt,
                                                       int* __restrict__ rank) {
    int e = blockIdx.x * BS + threadIdx.x;
    if (e < E) rank[e] = atomicAdd(&cnt[ei[E + e]], 1);
}

__global__ __launch_bounds__(BS) void bsum_kernel(const int* __restrict__ cnt, int n,
                                                  int* __restrict__ bsum) {
    __shared__ int s[BS];
    int t = threadIdx.x;
    int i = blockIdx.x * BS + t;
    s[t] = (i < n) ? cnt[i] : 0;
    __syncthreads();
    for (int st = BS / 2; st > 0; st >>= 1) {
        if (t < st) s[t] += s[t + st];
        __syncthreads();
    }
    if (t == 0) bsum[blockIdx.x] = s[0];
}

__global__ __launch_bounds__(512) void bscan_kernel(const int* __restrict__ bsum, int nb,
                                                    int* __restrict__ bpre) {
    __shared__ int s[512];
    int t = threadIdx.x;
    int v = (t < nb) ? bsum[t] : 0;
    s[t] = v;
    __syncthreads();
    for (int off = 1; off < 512; off <<= 1) {
        int add = (t >= off) ? s[t - off] : 0;
        __syncthreads();
        s[t] += add;
        __syncthreads();
    }
    if (t < nb) bpre[t] = s[t] - v;  // exclusive
}

__global__ __launch_bounds__(BS) void scan_kernel(const int* __restrict__ cnt, int n,
                                                  const int* __restrict__ bpre,
                                                  int* __restrict__ row_ptr) {
    __shared__ int s[BS];
    int t = threadIdx.x;
    int i = blockIdx.x * BS + t;
    int v = (i < n) ? cnt[i] : 0;
    s[t] = v;
    __syncthreads();
    for (int off = 1; off < BS; off <<= 1) {
        int add = (t >= off) ? s[t - off] : 0;
        __syncthreads();
        s[t] += add;
        __syncthreads();
    }
    if (i < n) row_ptr[i] = bpre[blockIdx.x] + s[t] - v;
}

__global__ __launch_bounds__(BS) void scatter_kernel(const int* __restrict__ ei, int E,
                                                     const int* __restrict__ row_ptr,
                                                     const int* __restrict__ rank,
                                                     int2* __restrict__ sedge) {
    int e = blockIdx.x * BS + threadIdx.x;
    if (e < E) {
        int d = ei[E + e];
        int p = row_ptr[d] + rank[e];
        sedge[p] = make_int2(ei[e], d);
    }
}

// ---------------- fused edge-MLP + block-segmented max ----------------

template <int IN_DIM>
__global__ __launch_bounds__(BS, IN_DIM == 6 ? 8 : 5) void edge_seg_kernel(
    const float4* __restrict__ pos4, const int* __restrict__ row_ptr,
    const int* __restrict__ cnt, const int2* __restrict__ sedge,
    const float* __restrict__ hfeat, const float* __restrict__ Wa,
    const float* __restrict__ ba, const float* __restrict__ Wb, const float* __restrict__ bb,
    unsigned* __restrict__ agg, int E) {
    __shared__ unsigned sm32[BS * 17];  // [edge][16 bf16-pairs + 1 pad]

    const int tid = threadIdx.x;
    const int k0 = blockIdx.x * BS;
    const int blockEnd = min(k0 + BS, E);
    const int k = min(k0 + tid, E - 1);  // clamp, no divergence

    const int2 ed = sedge[k];
    const int src = ed.x;
    const int dst = ed.y;

    const float4 ps = pos4[src];
    const float4 pd = pos4[dst];
    const float rx = ps.x - pd.x;
    const float ry = ps.y - pd.y;
    const float rz = ps.z - pd.z;

    float feat[IN_DIM];
    if constexpr (IN_DIM == 6) {
        feat[0] = ps.x;
        feat[1] = ps.y;
        feat[2] = ps.z;
        feat[3] = rx;
        feat[4] = ry;
        feat[5] = rz;
    } else {
        const float4* hp = reinterpret_cast<const float4*>(hfeat + (size_t)src * 32);
#pragma unroll
        for (int q = 0; q < 8; ++q) {
            float4 v = hp[q];
            feat[q * 4 + 0] = v.x;
            feat[q * 4 + 1] = v.y;
            feat[q * 4 + 2] = v.z;
            feat[q * 4 + 3] = v.w;
        }
        feat[32] = rx;
        feat[33] = ry;
        feat[34] = rz;
    }

    // hidden = relu(feat @ Wa + ba): i OUTER, 16 live v2f accumulators
    v2f acc[16];
#pragma unroll
    for (int g = 0; g < 16; ++g) acc[g] = *reinterpret_cast<const v2f*>(&ba[g * 2]);
#pragma unroll
    for (int i = 0; i < IN_DIM; ++i) {
        const v2f f = {feat[i], feat[i]};
#pragma unroll
        for (int g = 0; g < 16; ++g) {
            const v2f w = *reinterpret_cast<const v2f*>(&Wa[i * 32 + g * 2]);
            acc[g] = __builtin_elementwise_fma(f, w, acc[g]);
        }
    }
    float hid[32];
#pragma unroll
    for (int g = 0; g < 16; ++g) {
        const v2f z = {0.0f, 0.0f};
        const v2f r = __builtin_elementwise_max(acc[g], z);
        hid[g * 2 + 0] = r.x;
        hid[g * 2 + 1] = r.y;
    }

    // m = hidden @ Wb + bb: h OUTER
#pragma unroll
    for (int g = 0; g < 16; ++g) acc[g] = *reinterpret_cast<const v2f*>(&bb[g * 2]);
#pragma unroll
    for (int h = 0; h < 32; ++h) {
        const v2f f = {hid[h], hid[h]};
#pragma unroll
        for (int g = 0; g < 16; ++g) {
            const v2f w = *reinterpret_cast<const v2f*>(&Wb[h * 32 + g * 2]);
            acc[g] = __builtin_elementwise_fma(f, w, acc[g]);
        }
    }
    // pack to bf16 pairs in LDS
#pragma unroll
    for (int g = 0; g < 16; ++g) sm32[tid * 17 + g] = pack_bf16_rne(acc[g].x, acc[g].y);
    __syncthreads();

    // phase 2: segmented max; one (node, channel-pair) per lane-iteration
    const int d0 = sedge[k0].y;
    const int d1 = sedge[blockEnd - 1].y;
    const int nPairs = (d1 - d0 + 1) * 16;
    for (int idx = tid; idx < nPairs; idx += BS) {
        const int g = idx & 15;
        const int n = d0 + (idx >> 4);
        const int rs = row_ptr[n];
        const int re = rs + cnt[n];
        const int s0 = max(rs, k0);
        const int s1 = min(re, blockEnd);
        if (s0 >= s1) continue;
        v2f m0 = {-INFINITY, -INFINITY};
        v2f m1 = m0;
        int e = s0;
        for (; e + 2 <= s1; e += 2) {
            const unsigned u0 = sm32[(e - k0) * 17 + g];
            const unsigned u1 = sm32[(e - k0 + 1) * 17 + g];
            v2f a, b;
            a.x = __uint_as_float(u0 << 16);
            a.y = __uint_as_float(u0 & 0xFFFF0000u);
            b.x = __uint_as_float(u1 << 16);
            b.y = __uint_as_float(u1 & 0xFFFF0000u);
            m0 = __builtin_elementwise_max(m0, a);
            m1 = __builtin_elementwise_max(m1, b);
        }
        if (e < s1) {
            const unsigned u0 = sm32[(e - k0) * 17 + g];
            v2f a;
            a.x = __uint_as_float(u0 << 16);
            a.y = __uint_as_float(u0 & 0xFFFF0000u);
            m0 = __builtin_elementwise_max(m0, a);
        }
        const v2f m = __builtin_elementwise_max(m0, m1);
        unsigned* p = &agg[(size_t)n * 32 + g * 2];
        const unsigned e0 = ordenc(m.x);
        const unsigned e1 = ordenc(m.y);
        if (rs >= k0 && re <= blockEnd) {
            *reinterpret_cast<uint2*>(p) = make_uint2(e0, e1);  // interior node
        } else {
            atomicMax(p + 0, e0);  // straddles block boundary
            atomicMax(p + 1, e1);
        }
    }
}

extern "C" void kernel_launch(void* const* d_in, const int* in_sizes, int n_in,
                              void* d_out, int out_size, void* d_ws, size_t ws_size,
                              hipStream_t stream) {
    const float* pos = (const float*)d_in[0];
    const int* ei = (const int*)d_in[1];
    const float* W1 = (const float*)d_in[3];
    const float* b1 = (const float*)d_in[4];
    const float* W2 = (const float*)d_in[5];
    const float* b2 = (const float*)d_in[6];
    const float* W3 = (const float*)d_in[7];
    const float* b3 = (const float*)d_in[8];
    const float* W4 = (const float*)d_in[9];
    const float* b4 = (const float*)d_in[10];

    const int E = in_sizes[1] / 2;
    const int N = in_sizes[0] / 3;
    const int n32 = N * 32;
    const int E4 = ((E + 3) / 4) * 4;
    const int NPAD = ((N + BS - 1) / BS) * BS;
    const int NB = (N + BS - 1) / BS;  // <= 512
    const int EB = (E + BS - 1) / BS;

    int* cnt = (int*)d_ws;              // NPAD
    int* row_ptr = cnt + NPAD;          // NPAD
    int* rank = row_ptr + NPAD;         // E4
    int2* sedge = (int2*)(rank + E4);   // E4 (8B each)
    int* bsum = (int*)(sedge + E4);     // 512
    int* bpre = bsum + 512;             // 512
    float4* pos4 = (float4*)(bpre + 512);      // NPAD (16B-aligned: offset mult of 4 ints)
    unsigned* aggA = (unsigned*)(pos4 + NPAD); // n32: layer-1 agg -> h1 (float, in place)
    unsigned* aggB = (unsigned*)d_out;         // layer-2 agg -> final output

    const int gridN32 = (n32 + BS - 1) / BS;

    // CSR build (shared by both layers)
    init_kernel<<<gridN32, BS, 0, stream>>>(pos, pos4, cnt, N, aggA, aggB, n32);
    hist_rank_kernel<<<EB, BS, 0, stream>>>(ei, E, cnt, rank);
    bsum_kernel<<<NB, BS, 0, stream>>>(cnt, N, bsum);
    bscan_kernel<<<1, 512, 0, stream>>>(bsum, NB, bpre);
    scan_kernel<<<NB, BS, 0, stream>>>(cnt, N, bpre, row_ptr);
    scatter_kernel<<<EB, BS, 0, stream>>>(ei, E, row_ptr, rank, sedge);

    edge_seg_kernel<6><<<EB, BS, 0, stream>>>(pos4, row_ptr, cnt, sedge, nullptr, W1, b1, W2,
                                              b2, aggA, E);
    finalize_kernel<<<gridN32, BS, 0, stream>>>(aggA, n32);  // -> h1 floats

    edge_seg_kernel<35><<<EB, BS, 0, stream>>>(pos4, row_ptr, cnt, sedge, (const float*)aggA,
                                               W3, b3, W4, b4, aggB, E);
    finalize_kernel<<<gridN32, BS, 0, stream>>>(aggB, n32);
}